// Round 5
// baseline (610.184 us; speedup 1.0000x reference)
//
#include <hip/hip_runtime.h>
#include <math.h>

#define N 4096
#define D 256
#define NPOS 32768
#define TEMP 0.07f
#define INVT (1.0f / 0.07f)
#define BIGF 3.0e38f

#define BM 64        // tile rows/cols
#define KB 16        // k-chunk
#define NT (N / BM)  // 64 tile-blocks per dim
#define NTRI (NT * (NT + 1) / 2)  // 2080 upper-triangle tiles

// workspace layout (floats):
// [0 .. NT*N)          pmin[c][r]  per-(col-tile, row) local min
// [NT*N .. 2*NT*N)     psum[c][r]  per-(col-tile, row) min-scaled expsum
// [2*NT*N .. +N)       t[r] = TEMP*log(expsum_r) - dmin_r
// [2*NT*N + N]         loss accumulator
#define WS_PMIN 0
#define WS_PSUM (NT * N)
#define WS_T    (2 * NT * N)
#define WS_ACC  (2 * NT * N + N)

__global__ void init_acc_k(float* ws) {
    if (threadIdx.x == 0 && blockIdx.x == 0) ws[WS_ACC] = 0.0f;
}

// One wave per 64x64 tile, 8x8 micro-tile per lane. Single-wave workgroup:
// no s_barrier needed (per-wave LDS ops are in-order); lgkmcnt-only waits
// keep the global prefetch (vmcnt) in flight across the "barrier".
// LDS transposed [k][m]: writes bank=lane%32 (2-way, free); reads are 8
// distinct b128 addrs with 8-lane broadcast (conflict-free; R4 measured 0).
__global__ __launch_bounds__(64, 2)
void dist_tile_k(const float* __restrict__ x,
                 float* __restrict__ pmin, float* __restrict__ psum) {
    // triangular decode: blockIdx.x -> (bm, bn), bm <= bn
    {
    }
    const int t = blockIdx.x;
    const int u = (NTRI - 1) - t;
    int r = (int)((sqrtf((float)(8 * u + 1)) - 1.0f) * 0.5f);
    while (r * (r + 1) / 2 > u) --r;
    while ((r + 1) * (r + 2) / 2 <= u) ++r;
    const int bm = (NT - 1) - r;
    const int bn = (NT - 1) - (u - r * (r + 1) / 2);
    const bool diag = (bm == bn);

    const int lane = threadIdx.x;   // 0..63
    const int tx = lane & 7;        // col group
    const int ty = lane >> 3;       // row group

    __shared__ float As[KB][BM];
    __shared__ float Bs[KB][BM];

    float acc[2][2][4][4];  // [rh][ch][i][j]
#pragma unroll
    for (int rh = 0; rh < 2; ++rh)
#pragma unroll
        for (int ch = 0; ch < 2; ++ch)
#pragma unroll
            for (int i = 0; i < 4; ++i)
#pragma unroll
                for (int j = 0; j < 4; ++j) acc[rh][ch][i][j] = 0.0f;

    const int rowA0 = bm * BM;
    const int rowB0 = bn * BM;
    const float* xa = x + (size_t)(rowA0 + lane) * D;
    const float* xb = x + (size_t)(rowB0 + lane) * D;

    float4 pa[4], pb[4];
#pragma unroll
    for (int c = 0; c < 4; ++c) pa[c] = *(const float4*)(xa + 4 * c);
#pragma unroll
    for (int c = 0; c < 4; ++c) pb[c] = *(const float4*)(xb + 4 * c);

    for (int k0 = 0; k0 < D; k0 += KB) {
        // WAR: previous inner-loop ds_reads complete before overwrite.
        // (per-wave LDS FIFO already orders this; the wait pins the compiler)
        asm volatile("s_waitcnt lgkmcnt(0)" ::: "memory");
#pragma unroll
        for (int c = 0; c < 4; ++c) {
            As[4 * c + 0][lane] = pa[c].x; As[4 * c + 1][lane] = pa[c].y;
            As[4 * c + 2][lane] = pa[c].z; As[4 * c + 3][lane] = pa[c].w;
            Bs[4 * c + 0][lane] = pb[c].x; Bs[4 * c + 1][lane] = pb[c].y;
            Bs[4 * c + 2][lane] = pb[c].z; Bs[4 * c + 3][lane] = pb[c].w;
        }
        // prefetch next chunk while this chunk computes (vmcnt stays open)
        if (k0 + KB < D) {
#pragma unroll
            for (int c = 0; c < 4; ++c)
                pa[c] = *(const float4*)(xa + k0 + KB + 4 * c);
#pragma unroll
            for (int c = 0; c < 4; ++c)
                pb[c] = *(const float4*)(xb + k0 + KB + 4 * c);
        }
        // RAW: staging writes land before fragment reads.
        asm volatile("s_waitcnt lgkmcnt(0)" ::: "memory");

#pragma unroll
        for (int k = 0; k < KB; ++k) {
            const float4 alo = *(const float4*)&As[k][ty * 4];
            const float4 ahi = *(const float4*)&As[k][32 + ty * 4];
            const float4 blo = *(const float4*)&Bs[k][tx * 4];
            const float4 bhi = *(const float4*)&Bs[k][32 + tx * 4];
            const float av[2][4] = {{alo.x, alo.y, alo.z, alo.w},
                                    {ahi.x, ahi.y, ahi.z, ahi.w}};
            const float bv[2][4] = {{blo.x, blo.y, blo.z, blo.w},
                                    {bhi.x, bhi.y, bhi.z, bhi.w}};
#pragma unroll
            for (int rh = 0; rh < 2; ++rh)
#pragma unroll
                for (int ch = 0; ch < 2; ++ch)
#pragma unroll
                    for (int i = 0; i < 4; ++i)
#pragma unroll
                        for (int j = 0; j < 4; ++j)
                            acc[rh][ch][i][j] += fabsf(av[rh][i] - bv[ch][j]);
        }
    }

    // diagonal exclusion: poison self-distance (min skips it, exp -> 0)
    if (diag) {
#pragma unroll
        for (int rh = 0; rh < 2; ++rh)
#pragma unroll
            for (int ch = 0; ch < 2; ++ch)
#pragma unroll
                for (int i = 0; i < 4; ++i)
#pragma unroll
                    for (int j = 0; j < 4; ++j)
                        if (rh * 32 + ty * 4 + i == ch * 32 + tx * 4 + j)
                            acc[rh][ch][i][j] = BIGF;
    }

    // ---- row stats: reduce over cols = my 8 cols + shfl across tx lanes ----
#pragma unroll
    for (int rh = 0; rh < 2; ++rh) {
#pragma unroll
        for (int i = 0; i < 4; ++i) {
            float m = BIGF;
#pragma unroll
            for (int ch = 0; ch < 2; ++ch)
#pragma unroll
                for (int j = 0; j < 4; ++j) m = fminf(m, acc[rh][ch][i][j]);
            m = fminf(m, __shfl_xor(m, 1, 64));
            m = fminf(m, __shfl_xor(m, 2, 64));
            m = fminf(m, __shfl_xor(m, 4, 64));
            float s = 0.0f;
#pragma unroll
            for (int ch = 0; ch < 2; ++ch)
#pragma unroll
                for (int j = 0; j < 4; ++j)
                    s += __expf((m - acc[rh][ch][i][j]) * INVT);
            s += __shfl_xor(s, 1, 64);
            s += __shfl_xor(s, 2, 64);
            s += __shfl_xor(s, 4, 64);
            if (tx == 0) {
                const size_t idx = (size_t)bn * N + rowA0 + rh * 32 + ty * 4 + i;
                pmin[idx] = m;
                psum[idx] = s;
            }
        }
    }

    // ---- col stats: reduce over rows = my 8 rows + shfl across ty lanes ----
    if (!diag) {  // diag tile's col stats duplicate its row stats
#pragma unroll
        for (int ch = 0; ch < 2; ++ch) {
#pragma unroll
            for (int j = 0; j < 4; ++j) {
                float m = BIGF;
#pragma unroll
                for (int rh = 0; rh < 2; ++rh)
#pragma unroll
                    for (int i = 0; i < 4; ++i) m = fminf(m, acc[rh][ch][i][j]);
                m = fminf(m, __shfl_xor(m, 8, 64));
                m = fminf(m, __shfl_xor(m, 16, 64));
                m = fminf(m, __shfl_xor(m, 32, 64));
                float s = 0.0f;
#pragma unroll
                for (int rh = 0; rh < 2; ++rh)
#pragma unroll
                    for (int i = 0; i < 4; ++i)
                        s += __expf((m - acc[rh][ch][i][j]) * INVT);
                s += __shfl_xor(s, 8, 64);
                s += __shfl_xor(s, 16, 64);
                s += __shfl_xor(s, 32, 64);
                if (ty == 0) {
                    const size_t idx = (size_t)bm * N + rowB0 + ch * 32 + tx * 4 + j;
                    pmin[idx] = m;
                    psum[idx] = s;
                }
            }
        }
    }
}

// Merge the 64 per-tile partials per row: global min, rescaled expsum.
__global__ __launch_bounds__(256)
void row_stats_k(const float* __restrict__ ws_pmin,
                 const float* __restrict__ ws_psum, float* __restrict__ t) {
    const int r = blockIdx.x * 256 + threadIdx.x;
    float m = BIGF;
#pragma unroll 8
    for (int c = 0; c < NT; ++c) m = fminf(m, ws_pmin[(size_t)c * N + r]);
    float s = 0.0f;
#pragma unroll 8
    for (int c = 0; c < NT; ++c)
        s += ws_psum[(size_t)c * N + r] *
             __expf((m - ws_pmin[(size_t)c * N + r]) * INVT);
    t[r] = TEMP * __logf(s) - m;
}

// 256 blocks x 4 waves; each wave handles 32 pairs sequentially.
__global__ __launch_bounds__(256)
void pair_k(const float* __restrict__ x, const int* __restrict__ row,
            const int* __restrict__ col, const float* __restrict__ t,
            float* __restrict__ acc) {
    const int lane = threadIdx.x & 63;
    const int wave = threadIdx.x >> 6;
    float wsum = 0.0f;
    for (int it = 0; it < 32; ++it) {
        const int p = blockIdx.x * 128 + wave * 32 + it;
        const int r = row[p];
        const int c = col[p];
        const float4 a = *(const float4*)&x[(size_t)r * D + lane * 4];
        const float4 b = *(const float4*)&x[(size_t)c * D + lane * 4];
        float d = fabsf(a.x - b.x) + fabsf(a.y - b.y) +
                  fabsf(a.z - b.z) + fabsf(a.w - b.w);
#pragma unroll
        for (int off = 32; off > 0; off >>= 1) d += __shfl_xor(d, off, 64);
        if (lane == 0) wsum += d + t[r];
    }
    if (lane == 0) atomicAdd(acc, wsum);
}

__global__ void finalize_k(const float* __restrict__ acc, float* __restrict__ out) {
    if (threadIdx.x == 0 && blockIdx.x == 0)
        out[0] = acc[0] * (1.0f / (float)NPOS);
}

extern "C" void kernel_launch(void* const* d_in, const int* in_sizes, int n_in,
                              void* d_out, int out_size, void* d_ws, size_t ws_size,
                              hipStream_t stream) {
    const float* x = (const float*)d_in[0];
    const int* row = (const int*)d_in[1];
    const int* col = (const int*)d_in[2];
    float* ws = (float*)d_ws;
    float* out = (float*)d_out;

    init_acc_k<<<1, 64, 0, stream>>>(ws);

    dist_tile_k<<<NTRI, 64, 0, stream>>>(x, ws + WS_PMIN, ws + WS_PSUM);

    row_stats_k<<<N / 256, 256, 0, stream>>>(ws + WS_PMIN, ws + WS_PSUM, ws + WS_T);

    pair_k<<<NPOS / 128, 256, 0, stream>>>(x, row, col, ws + WS_T, ws + WS_ACC);

    finalize_k<<<1, 64, 0, stream>>>(ws + WS_ACC, out);
}

// Round 6
// 306.906 us; speedup vs baseline: 1.9882x; 1.9882x over previous
//
#include <hip/hip_runtime.h>
#include <math.h>

typedef _Float16 half2_t __attribute__((ext_vector_type(2)));

#define N 4096
#define D 256
#define NPOS 32768
#define TEMP 0.07f
#define INVT (1.0f / 0.07f)
#define BIGF 3.0e38f

#define BM 64          // tile rows/cols
#define KB 32          // k per chunk
#define KB2 (KB / 2)   // half2 per chunk
#define NT (N / BM)    // 64 tile-blocks per dim

// workspace layout (floats):
// [0 .. NT*N)          pmin[c][r]
// [NT*N .. 2*NT*N)     psum[c][r]
// [2*NT*N .. +N)       t[r]
// [2*NT*N + N]         loss accumulator
// [2*NT*N + N + 1 ..)  xh: N*(D/2) uints of packed half2
#define WS_PMIN 0
#define WS_PSUM (NT * N)
#define WS_T    (2 * NT * N)
#define WS_ACC  (2 * NT * N + N)
#define WS_XH   (2 * NT * N + N + 1)

__global__ void init_acc_k(float* ws) {
    if (threadIdx.x == 0 && blockIdx.x == 0) ws[WS_ACC] = 0.0f;
}

// pack f32 x -> half2 (one uint per 2 elements), row-major
__global__ __launch_bounds__(256)
void cvt_k(const float* __restrict__ x, unsigned int* __restrict__ xh) {
    const int i = blockIdx.x * 256 + threadIdx.x;  // over N*D/2
    const float2 v = ((const float2*)x)[i];
    half2_t h;
    h.x = (_Float16)v.x;
    h.y = (_Float16)v.y;
    xh[i] = __builtin_bit_cast(unsigned int, h);
}

// One wave per 64x64 tile, 8x8 micro-tile per lane. Packed-f16 diffs,
// f32 accumulation via v_dot2_f32_f16. LDS [k2][m] transposed: writes
// bank=lane%32 (2-way, free); reads 8 distinct b128 addrs, 8-lane
// broadcast (R4 measured 0 conflicts).
__global__ __launch_bounds__(64, 3)
void dist_tile_k(const unsigned int* __restrict__ xh,
                 float* __restrict__ pmin, float* __restrict__ psum) {
    const int bm = blockIdx.x;
    const int bn = blockIdx.y;
    if (bn < bm) return;  // d symmetric: upper triangle only
    const bool diag = (bm == bn);

    const int lane = threadIdx.x;   // 0..63
    const int tx = lane & 7;        // col group
    const int ty = lane >> 3;       // row group

    __shared__ unsigned int As[KB2][BM];  // 4 KB
    __shared__ unsigned int Bs[KB2][BM];

    float acc[2][2][4][4];  // [rh][ch][i][j]
#pragma unroll
    for (int rh = 0; rh < 2; ++rh)
#pragma unroll
        for (int ch = 0; ch < 2; ++ch)
#pragma unroll
            for (int i = 0; i < 4; ++i)
#pragma unroll
                for (int j = 0; j < 4; ++j) acc[rh][ch][i][j] = 0.0f;

    const int rowA0 = bm * BM;
    const int rowB0 = bn * BM;
    const unsigned int* ga = xh + (size_t)(rowA0 + lane) * (D / 2);
    const unsigned int* gb = xh + (size_t)(rowB0 + lane) * (D / 2);

    half2_t one2;
    one2.x = (_Float16)1.0f;
    one2.y = (_Float16)1.0f;

    for (int k0 = 0; k0 < D / 2; k0 += KB2) {
        uint4 la[KB2 / 4], lb[KB2 / 4];
#pragma unroll
        for (int c = 0; c < KB2 / 4; ++c) la[c] = *(const uint4*)(ga + k0 + 4 * c);
#pragma unroll
        for (int c = 0; c < KB2 / 4; ++c) lb[c] = *(const uint4*)(gb + k0 + 4 * c);
        __syncthreads();
#pragma unroll
        for (int c = 0; c < KB2 / 4; ++c) {
            As[4 * c + 0][lane] = la[c].x; As[4 * c + 1][lane] = la[c].y;
            As[4 * c + 2][lane] = la[c].z; As[4 * c + 3][lane] = la[c].w;
            Bs[4 * c + 0][lane] = lb[c].x; Bs[4 * c + 1][lane] = lb[c].y;
            Bs[4 * c + 2][lane] = lb[c].z; Bs[4 * c + 3][lane] = lb[c].w;
        }
        __syncthreads();

#pragma unroll
        for (int k2 = 0; k2 < KB2; ++k2) {
            const uint4 alo = *(const uint4*)&As[k2][ty * 4];
            const uint4 ahi = *(const uint4*)&As[k2][32 + ty * 4];
            const uint4 blo = *(const uint4*)&Bs[k2][tx * 4];
            const uint4 bhi = *(const uint4*)&Bs[k2][32 + tx * 4];
            const unsigned int av[2][4] = {{alo.x, alo.y, alo.z, alo.w},
                                           {ahi.x, ahi.y, ahi.z, ahi.w}};
            const unsigned int bv[2][4] = {{blo.x, blo.y, blo.z, blo.w},
                                           {bhi.x, bhi.y, bhi.z, bhi.w}};
#pragma unroll
            for (int rh = 0; rh < 2; ++rh)
#pragma unroll
                for (int ch = 0; ch < 2; ++ch)
#pragma unroll
                    for (int i = 0; i < 4; ++i)
#pragma unroll
                        for (int j = 0; j < 4; ++j) {
                            const half2_t a = __builtin_bit_cast(half2_t, av[rh][i]);
                            const half2_t b = __builtin_bit_cast(half2_t, bv[ch][j]);
                            const half2_t d = a - b;                       // v_pk_add_f16 (neg)
                            const unsigned int ad =
                                __builtin_bit_cast(unsigned int, d) & 0x7FFF7FFFu;  // |.| both halves
                            acc[rh][ch][i][j] = __builtin_amdgcn_fdot2(
                                __builtin_bit_cast(half2_t, ad), one2,
                                acc[rh][ch][i][j], false);                 // f32 += |dx|+|dy|
                        }
        }
    }

    // diagonal exclusion: poison self-distance (min skips it, exp -> 0)
    if (diag) {
#pragma unroll
        for (int rh = 0; rh < 2; ++rh)
#pragma unroll
            for (int ch = 0; ch < 2; ++ch)
#pragma unroll
                for (int i = 0; i < 4; ++i)
#pragma unroll
                    for (int j = 0; j < 4; ++j)
                        if (rh * 32 + ty * 4 + i == ch * 32 + tx * 4 + j)
                            acc[rh][ch][i][j] = BIGF;
    }

    // ---- row stats: my 8 cols + shfl across tx lanes ----
#pragma unroll
    for (int rh = 0; rh < 2; ++rh) {
#pragma unroll
        for (int i = 0; i < 4; ++i) {
            float m = BIGF;
#pragma unroll
            for (int ch = 0; ch < 2; ++ch)
#pragma unroll
                for (int j = 0; j < 4; ++j) m = fminf(m, acc[rh][ch][i][j]);
            m = fminf(m, __shfl_xor(m, 1, 64));
            m = fminf(m, __shfl_xor(m, 2, 64));
            m = fminf(m, __shfl_xor(m, 4, 64));
            float s = 0.0f;
#pragma unroll
            for (int ch = 0; ch < 2; ++ch)
#pragma unroll
                for (int j = 0; j < 4; ++j)
                    s += __expf((m - acc[rh][ch][i][j]) * INVT);
            s += __shfl_xor(s, 1, 64);
            s += __shfl_xor(s, 2, 64);
            s += __shfl_xor(s, 4, 64);
            if (tx == 0) {
                const size_t idx = (size_t)bn * N + rowA0 + rh * 32 + ty * 4 + i;
                pmin[idx] = m;
                psum[idx] = s;
            }
        }
    }

    // ---- col stats: my 8 rows + shfl across ty lanes ----
    if (!diag) {
#pragma unroll
        for (int ch = 0; ch < 2; ++ch) {
#pragma unroll
            for (int j = 0; j < 4; ++j) {
                float m = BIGF;
#pragma unroll
                for (int rh = 0; rh < 2; ++rh)
#pragma unroll
                    for (int i = 0; i < 4; ++i) m = fminf(m, acc[rh][ch][i][j]);
                m = fminf(m, __shfl_xor(m, 8, 64));
                m = fminf(m, __shfl_xor(m, 16, 64));
                m = fminf(m, __shfl_xor(m, 32, 64));
                float s = 0.0f;
#pragma unroll
                for (int rh = 0; rh < 2; ++rh)
#pragma unroll
                    for (int i = 0; i < 4; ++i)
                        s += __expf((m - acc[rh][ch][i][j]) * INVT);
                s += __shfl_xor(s, 8, 64);
                s += __shfl_xor(s, 16, 64);
                s += __shfl_xor(s, 32, 64);
                if (ty == 0) {
                    const size_t idx = (size_t)bm * N + rowB0 + ch * 32 + tx * 4 + j;
                    pmin[idx] = m;
                    psum[idx] = s;
                }
            }
        }
    }
}

// Merge the 64 per-tile partials per row: global min, rescaled expsum.
__global__ __launch_bounds__(256)
void row_stats_k(const float* __restrict__ ws_pmin,
                 const float* __restrict__ ws_psum, float* __restrict__ t) {
    const int r = blockIdx.x * 256 + threadIdx.x;
    float m = BIGF;
#pragma unroll 8
    for (int c = 0; c < NT; ++c) m = fminf(m, ws_pmin[(size_t)c * N + r]);
    float s = 0.0f;
#pragma unroll 8
    for (int c = 0; c < NT; ++c)
        s += ws_psum[(size_t)c * N + r] *
             __expf((m - ws_pmin[(size_t)c * N + r]) * INVT);
    t[r] = TEMP * __logf(s) - m;
}

// 256 blocks x 4 waves; each wave handles 32 pairs sequentially.
__global__ __launch_bounds__(256)
void pair_k(const float* __restrict__ x, const int* __restrict__ row,
            const int* __restrict__ col, const float* __restrict__ t,
            float* __restrict__ acc) {
    const int lane = threadIdx.x & 63;
    const int wave = threadIdx.x >> 6;
    float wsum = 0.0f;
    for (int it = 0; it < 32; ++it) {
        const int p = blockIdx.x * 128 + wave * 32 + it;
        const int r = row[p];
        const int c = col[p];
        const float4 a = *(const float4*)&x[(size_t)r * D + lane * 4];
        const float4 b = *(const float4*)&x[(size_t)c * D + lane * 4];
        float d = fabsf(a.x - b.x) + fabsf(a.y - b.y) +
                  fabsf(a.z - b.z) + fabsf(a.w - b.w);
#pragma unroll
        for (int off = 32; off > 0; off >>= 1) d += __shfl_xor(d, off, 64);
        if (lane == 0) wsum += d + t[r];
    }
    if (lane == 0) atomicAdd(acc, wsum);
}

__global__ void finalize_k(const float* __restrict__ acc, float* __restrict__ out) {
    if (threadIdx.x == 0 && blockIdx.x == 0)
        out[0] = acc[0] * (1.0f / (float)NPOS);
}

extern "C" void kernel_launch(void* const* d_in, const int* in_sizes, int n_in,
                              void* d_out, int out_size, void* d_ws, size_t ws_size,
                              hipStream_t stream) {
    const float* x = (const float*)d_in[0];
    const int* row = (const int*)d_in[1];
    const int* col = (const int*)d_in[2];
    float* ws = (float*)d_ws;
    float* out = (float*)d_out;
    unsigned int* xh = (unsigned int*)(ws + WS_XH);

    init_acc_k<<<1, 64, 0, stream>>>(ws);

    cvt_k<<<(N * D / 2) / 256, 256, 0, stream>>>(x, xh);

    dim3 grid(NT, NT);
    dist_tile_k<<<grid, 64, 0, stream>>>(xh, ws + WS_PMIN, ws + WS_PSUM);

    row_stats_k<<<N / 256, 256, 0, stream>>>(ws + WS_PMIN, ws + WS_PSUM, ws + WS_T);

    pair_k<<<NPOS / 128, 256, 0, stream>>>(x, row, col, ws + WS_T, ws + WS_ACC);

    finalize_k<<<1, 64, 0, stream>>>(ws + WS_ACC, out);
}

// Round 7
// 269.961 us; speedup vs baseline: 2.2603x; 1.1369x over previous
//
#include <hip/hip_runtime.h>
#include <math.h>

typedef _Float16 half2_t __attribute__((ext_vector_type(2)));

#define N 4096
#define D 256
#define NPOS 32768
#define TEMP 0.07f
#define INVT (1.0f / 0.07f)
#define BIGF 3.0e38f

#define KB 32          // k per chunk
#define KB2 (KB / 2)   // uints (half2) per chunk
#define NT 64          // 64x64 stat-tiles per dim (partials layout)
#define NT2 32         // 128x128 block-tiles per dim
#define NTRI2 (NT2 * (NT2 + 1) / 2)  // 528 triangle blocks

// workspace layout (floats):
// [0 .. NT*N)          pmin[c][r]   (c = 64-col-tile, r = row)
// [NT*N .. 2*NT*N)     psum[c][r]
// [2*NT*N .. +N)       t[r]
// [2*NT*N + N]         loss accumulator
// [2*NT*N + N + 1 ..)  xh: N*(D/2) uints of packed half2
#define WS_PMIN 0
#define WS_PSUM (NT * N)
#define WS_T    (2 * NT * N)
#define WS_ACC  (2 * NT * N + N)
#define WS_XH   (2 * NT * N + N + 1)

__global__ void init_acc_k(float* ws) {
    if (threadIdx.x == 0 && blockIdx.x == 0) ws[WS_ACC] = 0.0f;
}

// pack f32 x -> half2 (one uint per 2 elements), row-major
__global__ __launch_bounds__(256)
void cvt_k(const float* __restrict__ x, unsigned int* __restrict__ xh) {
    const int i = blockIdx.x * 256 + threadIdx.x;  // over N*D/2
    const float2 v = ((const float2*)x)[i];
    half2_t h;
    h.x = (_Float16)v.x;
    h.y = (_Float16)v.y;
    xh[i] = __builtin_bit_cast(unsigned int, h);
}

// 128x128 block-tile, 256 threads = 4 waves; wave (w0,w1) owns the 64x64
// quadrant (rows w0*64.., cols w1*64..) with an 8x8 micro-tile per lane.
// Packed-f16 diffs, f32 accumulation via v_dot2_f32_f16.
// LDS [k2][m] transposed; frag reads are 8 distinct b128 addrs with 8-lane
// broadcast (conflict-free, measured 0 in R4/R6).
__global__ __launch_bounds__(256, 2)
void dist_tile_k(const unsigned int* __restrict__ xh,
                 float* __restrict__ pmin, float* __restrict__ psum) {
    // triangular decode: blockIdx.x -> (bm, bn), bm <= bn (128-granularity)
    const int t = blockIdx.x;
    const int u = (NTRI2 - 1) - t;
    int r = (int)((sqrtf((float)(8 * u + 1)) - 1.0f) * 0.5f);
    while (r * (r + 1) / 2 > u) --r;
    while ((r + 1) * (r + 2) / 2 <= u) ++r;
    const int bm = (NT2 - 1) - r;
    const int bn = (NT2 - 1) - (u - r * (r + 1) / 2);

    const int tid = threadIdx.x;
    const int lane = tid & 63;
    const int w = tid >> 6;
    const int w0 = w >> 1;          // row quadrant
    const int w1 = w & 1;           // col quadrant
    const int tx = lane & 7;
    const int ty = lane >> 3;

    const int rt = 2 * bm + w0;     // this wave's 64-row-tile index
    const int ct = 2 * bn + w1;     // this wave's 64-col-tile index
    const bool diagq = (rt == ct);

    __shared__ unsigned int As[KB2][128];  // 8 KB
    __shared__ unsigned int Bs[KB2][128];  // 8 KB

    float acc[2][2][4][4];
#pragma unroll
    for (int rh = 0; rh < 2; ++rh)
#pragma unroll
        for (int ch = 0; ch < 2; ++ch)
#pragma unroll
            for (int i = 0; i < 4; ++i)
#pragma unroll
                for (int j = 0; j < 4; ++j) acc[rh][ch][i][j] = 0.0f;

    const int rowA0 = bm * 128;
    const int rowB0 = bn * 128;

    // staging: 512 uint4 per side per chunk; thread handles u4 = tid, tid+256
    const int sr = tid >> 2;        // 0..63 (row for first uint4)
    const int sc = tid & 3;         // 0..3  (uint4 col within chunk)
    const unsigned int* gaL = xh + (size_t)(rowA0 + sr) * (D / 2) + sc * 4;
    const unsigned int* gaH = xh + (size_t)(rowA0 + sr + 64) * (D / 2) + sc * 4;
    const unsigned int* gbL = xh + (size_t)(rowB0 + sr) * (D / 2) + sc * 4;
    const unsigned int* gbH = xh + (size_t)(rowB0 + sr + 64) * (D / 2) + sc * 4;

    half2_t one2;
    one2.x = (_Float16)1.0f;
    one2.y = (_Float16)1.0f;

    for (int k0 = 0; k0 < D / 2; k0 += KB2) {
        const uint4 laL = *(const uint4*)(gaL + k0);
        const uint4 laH = *(const uint4*)(gaH + k0);
        const uint4 lbL = *(const uint4*)(gbL + k0);
        const uint4 lbH = *(const uint4*)(gbH + k0);
        __syncthreads();
        As[sc * 4 + 0][sr] = laL.x; As[sc * 4 + 1][sr] = laL.y;
        As[sc * 4 + 2][sr] = laL.z; As[sc * 4 + 3][sr] = laL.w;
        As[sc * 4 + 0][sr + 64] = laH.x; As[sc * 4 + 1][sr + 64] = laH.y;
        As[sc * 4 + 2][sr + 64] = laH.z; As[sc * 4 + 3][sr + 64] = laH.w;
        Bs[sc * 4 + 0][sr] = lbL.x; Bs[sc * 4 + 1][sr] = lbL.y;
        Bs[sc * 4 + 2][sr] = lbL.z; Bs[sc * 4 + 3][sr] = lbL.w;
        Bs[sc * 4 + 0][sr + 64] = lbH.x; Bs[sc * 4 + 1][sr + 64] = lbH.y;
        Bs[sc * 4 + 2][sr + 64] = lbH.z; Bs[sc * 4 + 3][sr + 64] = lbH.w;
        __syncthreads();

#pragma unroll
        for (int k2 = 0; k2 < KB2; ++k2) {
            const uint4 alo = *(const uint4*)&As[k2][w0 * 64 + ty * 4];
            const uint4 ahi = *(const uint4*)&As[k2][w0 * 64 + 32 + ty * 4];
            const uint4 blo = *(const uint4*)&Bs[k2][w1 * 64 + tx * 4];
            const uint4 bhi = *(const uint4*)&Bs[k2][w1 * 64 + 32 + tx * 4];
            const unsigned int av[2][4] = {{alo.x, alo.y, alo.z, alo.w},
                                           {ahi.x, ahi.y, ahi.z, ahi.w}};
            const unsigned int bv[2][4] = {{blo.x, blo.y, blo.z, blo.w},
                                           {bhi.x, bhi.y, bhi.z, bhi.w}};
#pragma unroll
            for (int rh = 0; rh < 2; ++rh)
#pragma unroll
                for (int ch = 0; ch < 2; ++ch)
#pragma unroll
                    for (int i = 0; i < 4; ++i)
#pragma unroll
                        for (int j = 0; j < 4; ++j) {
                            const half2_t a = __builtin_bit_cast(half2_t, av[rh][i]);
                            const half2_t b = __builtin_bit_cast(half2_t, bv[ch][j]);
                            const half2_t d = a - b;
                            const unsigned int ad =
                                __builtin_bit_cast(unsigned int, d) & 0x7FFF7FFFu;
                            acc[rh][ch][i][j] = __builtin_amdgcn_fdot2(
                                __builtin_bit_cast(half2_t, ad), one2,
                                acc[rh][ch][i][j], false);
                        }
        }
    }

    // diagonal exclusion (only quadrants on the global diagonal)
    if (diagq) {
#pragma unroll
        for (int rh = 0; rh < 2; ++rh)
#pragma unroll
            for (int ch = 0; ch < 2; ++ch)
#pragma unroll
                for (int i = 0; i < 4; ++i)
#pragma unroll
                    for (int j = 0; j < 4; ++j)
                        if (rh * 32 + ty * 4 + i == ch * 32 + tx * 4 + j)
                            acc[rh][ch][i][j] = BIGF;
    }

    // ---- row stats (iff rt <= ct): my 8 cols + shfl across tx lanes ----
    if (rt <= ct) {
#pragma unroll
        for (int rh = 0; rh < 2; ++rh) {
#pragma unroll
            for (int i = 0; i < 4; ++i) {
                float m = BIGF;
#pragma unroll
                for (int ch = 0; ch < 2; ++ch)
#pragma unroll
                    for (int j = 0; j < 4; ++j) m = fminf(m, acc[rh][ch][i][j]);
                m = fminf(m, __shfl_xor(m, 1, 64));
                m = fminf(m, __shfl_xor(m, 2, 64));
                m = fminf(m, __shfl_xor(m, 4, 64));
                float s = 0.0f;
#pragma unroll
                for (int ch = 0; ch < 2; ++ch)
#pragma unroll
                    for (int j = 0; j < 4; ++j)
                        s += __expf((m - acc[rh][ch][i][j]) * INVT);
                s += __shfl_xor(s, 1, 64);
                s += __shfl_xor(s, 2, 64);
                s += __shfl_xor(s, 4, 64);
                if (tx == 0) {
                    const size_t idx =
                        (size_t)ct * N + rt * 64 + rh * 32 + ty * 4 + i;
                    pmin[idx] = m;
                    psum[idx] = s;
                }
            }
        }
    }

    // ---- col stats (iff rt < ct): my 8 rows + shfl across ty lanes ----
    if (rt < ct) {
#pragma unroll
        for (int ch = 0; ch < 2; ++ch) {
#pragma unroll
            for (int j = 0; j < 4; ++j) {
                float m = BIGF;
#pragma unroll
                for (int rh = 0; rh < 2; ++rh)
#pragma unroll
                    for (int i = 0; i < 4; ++i) m = fminf(m, acc[rh][ch][i][j]);
                m = fminf(m, __shfl_xor(m, 8, 64));
                m = fminf(m, __shfl_xor(m, 16, 64));
                m = fminf(m, __shfl_xor(m, 32, 64));
                float s = 0.0f;
#pragma unroll
                for (int rh = 0; rh < 2; ++rh)
#pragma unroll
                    for (int i = 0; i < 4; ++i)
                        s += __expf((m - acc[rh][ch][i][j]) * INVT);
                s += __shfl_xor(s, 8, 64);
                s += __shfl_xor(s, 16, 64);
                s += __shfl_xor(s, 32, 64);
                if (ty == 0) {
                    const size_t idx =
                        (size_t)rt * N + ct * 64 + ch * 32 + tx * 4 + j;
                    pmin[idx] = m;
                    psum[idx] = s;
                }
            }
        }
    }
}

// Merge the 64 per-tile partials per row: global min, rescaled expsum.
__global__ __launch_bounds__(256)
void row_stats_k(const float* __restrict__ ws_pmin,
                 const float* __restrict__ ws_psum, float* __restrict__ t) {
    const int r = blockIdx.x * 256 + threadIdx.x;
    float m = BIGF;
#pragma unroll 8
    for (int c = 0; c < NT; ++c) m = fminf(m, ws_pmin[(size_t)c * N + r]);
    float s = 0.0f;
#pragma unroll 8
    for (int c = 0; c < NT; ++c)
        s += ws_psum[(size_t)c * N + r] *
             __expf((m - ws_pmin[(size_t)c * N + r]) * INVT);
    t[r] = TEMP * __logf(s) - m;
}

// 512 blocks x 4 waves; each wave handles 16 pairs sequentially.
__global__ __launch_bounds__(256)
void pair_k(const float* __restrict__ x, const int* __restrict__ row,
            const int* __restrict__ col, const float* __restrict__ t,
            float* __restrict__ acc) {
    const int lane = threadIdx.x & 63;
    const int wave = threadIdx.x >> 6;
    float wsum = 0.0f;
    for (int it = 0; it < 16; ++it) {
        const int p = blockIdx.x * 64 + wave * 16 + it;
        const int r = row[p];
        const int c = col[p];
        const float4 a = *(const float4*)&x[(size_t)r * D + lane * 4];
        const float4 b = *(const float4*)&x[(size_t)c * D + lane * 4];
        float d = fabsf(a.x - b.x) + fabsf(a.y - b.y) +
                  fabsf(a.z - b.z) + fabsf(a.w - b.w);
#pragma unroll
        for (int off = 32; off > 0; off >>= 1) d += __shfl_xor(d, off, 64);
        if (lane == 0) wsum += d + t[r];
    }
    if (lane == 0) atomicAdd(acc, wsum);
}

__global__ void finalize_k(const float* __restrict__ acc, float* __restrict__ out) {
    if (threadIdx.x == 0 && blockIdx.x == 0)
        out[0] = acc[0] * (1.0f / (float)NPOS);
}

extern "C" void kernel_launch(void* const* d_in, const int* in_sizes, int n_in,
                              void* d_out, int out_size, void* d_ws, size_t ws_size,
                              hipStream_t stream) {
    const float* x = (const float*)d_in[0];
    const int* row = (const int*)d_in[1];
    const int* col = (const int*)d_in[2];
    float* ws = (float*)d_ws;
    float* out = (float*)d_out;
    unsigned int* xh = (unsigned int*)(ws + WS_XH);

    init_acc_k<<<1, 64, 0, stream>>>(ws);

    cvt_k<<<(N * D / 2) / 256, 256, 0, stream>>>(x, xh);

    dist_tile_k<<<NTRI2, 256, 0, stream>>>(xh, ws + WS_PMIN, ws + WS_PSUM);

    row_stats_k<<<N / 256, 256, 0, stream>>>(ws + WS_PMIN, ws + WS_PSUM, ws + WS_T);

    pair_k<<<NPOS / 64, 256, 0, stream>>>(x, row, col, ws + WS_T, ws + WS_ACC);

    finalize_k<<<1, 64, 0, stream>>>(ws + WS_ACC, out);
}

// Round 8
// 133.189 us; speedup vs baseline: 4.5813x; 2.0269x over previous
//
#include <hip/hip_runtime.h>
#include <math.h>

#define N 4096
#define D 256
#define NPOS 32768
#define TEMP 0.07f
#define INVT (1.0f / 0.07f)
#define BIGF 3.0e38f

#define RQ 5.5f                      // quantization range [-RQ, RQ]
#define QS (255.0f / (2.0f * RQ))    // f32 -> u8 scale
#define DEQ (2.0f * RQ / 255.0f)     // u8-units -> f32

#define NT 64          // 64-row stat-tiles per dim (partials layout)
#define NT2 32         // 128x128 block-tiles per dim
#define NTRI2 (NT2 * (NT2 + 1) / 2)  // 528 triangle blocks
#define KC 32          // k4 (u32) per D-chunk (=128 elements), 2 chunks

// workspace layout (floats):
// [0 .. N*64)         pmin[r][c]  (r = row, c = 64-col-tile)  row-major
// [N*64 .. 2*N*64)    psum[r][c]
// [2*N*64 .. +N)      t[r]
// [.. +1]             loss accumulator (float)
// [.. +1]             ticket counter (uint)
// [WS_XQ ..)          xq: N*(D/4) u32 of packed u8 quants
#define WS_PMIN 0
#define WS_PSUM (N * NT)
#define WS_T    (2 * N * NT)
#define WS_ACC  (2 * N * NT + N)
#define WS_CNT  (2 * N * NT + N + 1)
#define WS_XQ   (2 * N * NT + N + 4)   // 16B-aligned

__device__ __forceinline__ unsigned sad_u8(unsigned a, unsigned b, unsigned c) {
#if __has_builtin(__builtin_amdgcn_sad_u8)
    return __builtin_amdgcn_sad_u8(a, b, c);
#else
    unsigned d;
    asm("v_sad_u8 %0, %1, %2, %3" : "=v"(d) : "v"(a), "v"(b), "v"(c));
    return d;
#endif
}

__device__ __forceinline__ unsigned quant1(float v) {
    const float f = fminf(fmaxf((v + RQ) * QS, 0.0f), 255.0f);
    return (unsigned)__float2uint_rn(f);
}

// quantize f32 -> packed u8 (4/u32), and zero acc/ticket
__global__ __launch_bounds__(256)
void cvt_init_k(const float* __restrict__ x, unsigned* __restrict__ xq,
                float* __restrict__ acc, unsigned* __restrict__ cnt) {
    const int i = blockIdx.x * 256 + threadIdx.x;  // over N*D/4
    const float4 v = ((const float4*)x)[i];
    const unsigned q = quant1(v.x) | (quant1(v.y) << 8) |
                       (quant1(v.z) << 16) | (quant1(v.w) << 24);
    xq[i] = q;
    if (i == 0) { *acc = 0.0f; *cnt = 0u; }
}

// 128x128 block-tile, 256 threads = 4 waves; wave (w0,w1) owns a 64x64
// quadrant, 8x8 micro-tile per lane. u8 SAD inner loop (4 MACs/instr),
// u32 accumulators pinned to VGPRs by the asm "v" constraint.
// LDS [k4][m] transposed: staging stores bank=lane%32 (2-way free, R4/R6
// proven); frag reads 8 distinct b128 addrs, 8-lane broadcast (0 conflicts).
__global__ __launch_bounds__(256, 3)
void dist_tile_k(const unsigned* __restrict__ xq,
                 float* __restrict__ pmin, float* __restrict__ psum) {
    // triangular decode: blockIdx.x -> (bm, bn), bm <= bn
    const int tt = blockIdx.x;
    const int u = (NTRI2 - 1) - tt;
    int r = (int)((sqrtf((float)(8 * u + 1)) - 1.0f) * 0.5f);
    while (r * (r + 1) / 2 > u) --r;
    while ((r + 1) * (r + 2) / 2 <= u) ++r;
    const int bm = (NT2 - 1) - r;
    const int bn = (NT2 - 1) - (u - r * (r + 1) / 2);

    const int tid = threadIdx.x;
    const int lane = tid & 63;
    const int w = tid >> 6;
    const int w0 = w >> 1;          // row quadrant
    const int w1 = w & 1;           // col quadrant
    const int tx = lane & 7;
    const int ty = lane >> 3;

    const int rt = 2 * bm + w0;     // 64-row-tile index
    const int ct = 2 * bn + w1;     // 64-col-tile index
    const bool diagq = (rt == ct);

    __shared__ unsigned As[KC][128];  // 16 KB
    __shared__ unsigned Bs[KC][128];  // 16 KB

    unsigned uacc[2][2][4][4];
#pragma unroll
    for (int rh = 0; rh < 2; ++rh)
#pragma unroll
        for (int ch = 0; ch < 2; ++ch)
#pragma unroll
            for (int i = 0; i < 4; ++i)
#pragma unroll
                for (int j = 0; j < 4; ++j) uacc[rh][ch][i][j] = 0u;

    const int rowA0 = bm * 128;
    const int rowB0 = bn * 128;

    // staging: W0 -> A rows 0..63, W1 -> A 64..127, W2 -> B 0..63, W3 -> B 64..127
    const int srow = (w < 2 ? rowA0 : rowB0) + (w & 1) * 64 + lane;
    const uint4* grow = (const uint4*)(xq + (size_t)srow * (D / 4));
    unsigned (*S)[128] = (w < 2) ? As : Bs;
    const int m = (w & 1) * 64 + lane;

    const int aoff = w0 * 64;
    const int boff = w1 * 64;

    for (int chk = 0; chk < 2; ++chk) {
        uint4 L[8];
#pragma unroll
        for (int c = 0; c < 8; ++c) L[c] = grow[chk * 8 + c];
        __syncthreads();  // previous chunk's reads done before overwrite
#pragma unroll
        for (int c = 0; c < 8; ++c) {
            S[c * 4 + 0][m] = L[c].x; S[c * 4 + 1][m] = L[c].y;
            S[c * 4 + 2][m] = L[c].z; S[c * 4 + 3][m] = L[c].w;
        }
        __syncthreads();

#pragma unroll 8
        for (int k4 = 0; k4 < KC; ++k4) {
            const uint4 alo = *(const uint4*)&As[k4][aoff + ty * 4];
            const uint4 ahi = *(const uint4*)&As[k4][aoff + 32 + ty * 4];
            const uint4 blo = *(const uint4*)&Bs[k4][boff + tx * 4];
            const uint4 bhi = *(const uint4*)&Bs[k4][boff + 32 + tx * 4];
            const unsigned av[2][4] = {{alo.x, alo.y, alo.z, alo.w},
                                       {ahi.x, ahi.y, ahi.z, ahi.w}};
            const unsigned bv[2][4] = {{blo.x, blo.y, blo.z, blo.w},
                                       {bhi.x, bhi.y, bhi.z, bhi.w}};
#pragma unroll
            for (int rh = 0; rh < 2; ++rh)
#pragma unroll
                for (int chq = 0; chq < 2; ++chq)
#pragma unroll
                    for (int i = 0; i < 4; ++i)
#pragma unroll
                        for (int j = 0; j < 4; ++j)
                            uacc[rh][chq][i][j] =
                                sad_u8(av[rh][i], bv[chq][j], uacc[rh][chq][i][j]);
        }
    }

    // dequantize to float
    float acc[2][2][4][4];
#pragma unroll
    for (int rh = 0; rh < 2; ++rh)
#pragma unroll
        for (int chq = 0; chq < 2; ++chq)
#pragma unroll
            for (int i = 0; i < 4; ++i)
#pragma unroll
                for (int j = 0; j < 4; ++j)
                    acc[rh][chq][i][j] = (float)uacc[rh][chq][i][j] * DEQ;

    // diagonal exclusion: poison self-distance (min skips it, exp -> 0)
    if (diagq) {
#pragma unroll
        for (int rh = 0; rh < 2; ++rh)
#pragma unroll
            for (int chq = 0; chq < 2; ++chq)
#pragma unroll
                for (int i = 0; i < 4; ++i)
#pragma unroll
                    for (int j = 0; j < 4; ++j)
                        if (rh * 32 + ty * 4 + i == chq * 32 + tx * 4 + j)
                            acc[rh][chq][i][j] = BIGF;
    }

    // ---- row stats (iff rt <= ct): my 8 cols + shfl across tx lanes ----
    if (rt <= ct) {
#pragma unroll
        for (int rh = 0; rh < 2; ++rh) {
#pragma unroll
            for (int i = 0; i < 4; ++i) {
                float mn = BIGF;
#pragma unroll
                for (int chq = 0; chq < 2; ++chq)
#pragma unroll
                    for (int j = 0; j < 4; ++j) mn = fminf(mn, acc[rh][chq][i][j]);
                mn = fminf(mn, __shfl_xor(mn, 1, 64));
                mn = fminf(mn, __shfl_xor(mn, 2, 64));
                mn = fminf(mn, __shfl_xor(mn, 4, 64));
                float s = 0.0f;
#pragma unroll
                for (int chq = 0; chq < 2; ++chq)
#pragma unroll
                    for (int j = 0; j < 4; ++j)
                        s += __expf((mn - acc[rh][chq][i][j]) * INVT);
                s += __shfl_xor(s, 1, 64);
                s += __shfl_xor(s, 2, 64);
                s += __shfl_xor(s, 4, 64);
                if (tx == 0) {
                    const size_t idx =
                        (size_t)(rt * 64 + rh * 32 + ty * 4 + i) * NT + ct;
                    pmin[idx] = mn;
                    psum[idx] = s;
                }
            }
        }
    }

    // ---- col stats (iff rt < ct): my 8 rows + shfl across ty lanes ----
    if (rt < ct) {
#pragma unroll
        for (int chq = 0; chq < 2; ++chq) {
#pragma unroll
            for (int j = 0; j < 4; ++j) {
                float mn = BIGF;
#pragma unroll
                for (int rh = 0; rh < 2; ++rh)
#pragma unroll
                    for (int i = 0; i < 4; ++i) mn = fminf(mn, acc[rh][chq][i][j]);
                mn = fminf(mn, __shfl_xor(mn, 8, 64));
                mn = fminf(mn, __shfl_xor(mn, 16, 64));
                mn = fminf(mn, __shfl_xor(mn, 32, 64));
                float s = 0.0f;
#pragma unroll
                for (int rh = 0; rh < 2; ++rh)
#pragma unroll
                    for (int i = 0; i < 4; ++i)
                        s += __expf((mn - acc[rh][chq][i][j]) * INVT);
                s += __shfl_xor(s, 8, 64);
                s += __shfl_xor(s, 16, 64);
                s += __shfl_xor(s, 32, 64);
                if (ty == 0) {
                    const size_t idx =
                        (size_t)(ct * 64 + chq * 32 + tx * 4 + j) * NT + rt;
                    pmin[idx] = mn;
                    psum[idx] = s;
                }
            }
        }
    }
}

// One wave per row: coalesced read of the 64 partials, shuffle reduce.
__global__ __launch_bounds__(256)
void row_stats_k(const float* __restrict__ pmin, const float* __restrict__ psum,
                 float* __restrict__ t) {
    const int r = blockIdx.x * 4 + (threadIdx.x >> 6);
    const int c = threadIdx.x & 63;
    const float pm = pmin[(size_t)r * NT + c];
    const float ps = psum[(size_t)r * NT + c];
    float mn = pm;
#pragma unroll
    for (int off = 32; off > 0; off >>= 1) mn = fminf(mn, __shfl_xor(mn, off, 64));
    float s = ps * __expf((mn - pm) * INVT);
#pragma unroll
    for (int off = 32; off > 0; off >>= 1) s += __shfl_xor(s, off, 64);
    if (c == 0) t[r] = TEMP * __logf(s) - mn;
}

// 1024 blocks x 4 waves x 8 pairs; batched index+data loads; block-level
// atomic + ticket: last block finalizes the loss.
__global__ __launch_bounds__(256)
void pair_fin_k(const float* __restrict__ x, const int* __restrict__ row,
                const int* __restrict__ col, const float* __restrict__ t,
                float* __restrict__ acc, unsigned* __restrict__ cnt,
                float* __restrict__ out) {
    const int lane = threadIdx.x & 63;
    const int wave = threadIdx.x >> 6;
    const int p0 = (blockIdx.x * 4 + wave) * 8;

    int rp[8], cp[8];
#pragma unroll
    for (int i = 0; i < 8; ++i) { rp[i] = row[p0 + i]; cp[i] = col[p0 + i]; }
    float4 a[8], b[8];
#pragma unroll
    for (int i = 0; i < 8; ++i) {
        a[i] = *(const float4*)&x[(size_t)rp[i] * D + lane * 4];
        b[i] = *(const float4*)&x[(size_t)cp[i] * D + lane * 4];
    }
    float wsum = 0.0f;
#pragma unroll
    for (int i = 0; i < 8; ++i) {
        float d = fabsf(a[i].x - b[i].x) + fabsf(a[i].y - b[i].y) +
                  fabsf(a[i].z - b[i].z) + fabsf(a[i].w - b[i].w);
#pragma unroll
        for (int off = 32; off > 0; off >>= 1) d += __shfl_xor(d, off, 64);
        if (lane == 0) wsum += d + t[rp[i]];
    }

    __shared__ float bs[4];
    if (lane == 0) bs[wave] = wsum;
    __syncthreads();
    if (threadIdx.x == 0) {
        const float tot = bs[0] + bs[1] + bs[2] + bs[3];
        atomicAdd(acc, tot);
        __threadfence();
        const unsigned tk = atomicAdd(cnt, 1u);
        if (tk == (unsigned)(gridDim.x - 1)) {
            const float v = atomicAdd(acc, 0.0f);  // coherent read
            out[0] = v * (1.0f / (float)NPOS);
        }
    }
}

extern "C" void kernel_launch(void* const* d_in, const int* in_sizes, int n_in,
                              void* d_out, int out_size, void* d_ws, size_t ws_size,
                              hipStream_t stream) {
    const float* x = (const float*)d_in[0];
    const int* row = (const int*)d_in[1];
    const int* col = (const int*)d_in[2];
    float* ws = (float*)d_ws;
    float* out = (float*)d_out;
    unsigned* xq = (unsigned*)(ws + WS_XQ);
    float* acc = ws + WS_ACC;
    unsigned* cnt = (unsigned*)(ws + WS_CNT);

    cvt_init_k<<<(N * D / 4) / 256, 256, 0, stream>>>(x, xq, acc, cnt);

    dist_tile_k<<<NTRI2, 256, 0, stream>>>(xq, ws + WS_PMIN, ws + WS_PSUM);

    row_stats_k<<<N / 4, 256, 0, stream>>>(ws + WS_PMIN, ws + WS_PSUM, ws + WS_T);

    pair_fin_k<<<NPOS / 32, 256, 0, stream>>>(x, row, col, ws + WS_T, acc, cnt, out);
}